// Round 6
// baseline (347.927 us; speedup 1.0000x reference)
//
#include <hip/hip_runtime.h>

#define N_NODES 8192
#define HDIM    512
#define NEDGE   262144

typedef __attribute__((ext_vector_type(8))) short bf16x8;
typedef __attribute__((ext_vector_type(4))) float f32x4;

__device__ inline unsigned short f2bf(float f) {
  unsigned u = __float_as_uint(f);
  unsigned r = (u + 0x7FFFu + ((u >> 16) & 1u)) >> 16;
  return (unsigned short)r;
}
__device__ inline float bf2f(short s) {
  return __uint_as_float(((unsigned)(unsigned short)s) << 16);
}

__device__ inline void gload16(const void* g, void* l) {
  __builtin_amdgcn_global_load_lds(
      (const __attribute__((address_space(1))) unsigned*)g,
      (__attribute__((address_space(3))) unsigned*)l, 16, 0, 0);
}

// ---------------- CSR build ----------------
__global__ void zero_kernel(int* __restrict__ p) {
  p[blockIdx.x * 256 + threadIdx.x] = 0;
}

__global__ void hist_kernel(const int* __restrict__ rows, int* __restrict__ counts) {
  int e = blockIdx.x * 256 + threadIdx.x;
  atomicAdd(&counts[rows[e]], 1);
}

__global__ __launch_bounds__(1024) void scan_kernel(const int* __restrict__ counts,
                                                    int* __restrict__ offs,
                                                    int* __restrict__ cursor) {
  __shared__ int s[1024];
  int tid = threadIdx.x;
  int local[8];
  int sum = 0;
#pragma unroll
  for (int i = 0; i < 8; ++i) { local[i] = counts[tid * 8 + i]; sum += local[i]; }
  s[tid] = sum;
  __syncthreads();
  for (int d = 1; d < 1024; d <<= 1) {
    int v = (tid >= d) ? s[tid - d] : 0;
    __syncthreads();
    s[tid] += v;
    __syncthreads();
  }
  int base = (tid > 0) ? s[tid - 1] : 0;
#pragma unroll
  for (int i = 0; i < 8; ++i) {
    offs[tid * 8 + i] = base;
    cursor[tid * 8 + i] = base;
    base += local[i];
  }
  if (tid == 1023) offs[8192] = base;
}

__global__ void scatter_kernel(const int* __restrict__ rows, const int* __restrict__ cols,
                               const float* __restrict__ vals, int* cursor,
                               int2* __restrict__ edges) {
  int e = blockIdx.x * 256 + threadIdx.x;
  int slot = atomicAdd(&cursor[rows[e]], 1);
  edges[slot] = make_int2(cols[e], __float_as_int(vals[e]));
}

// ---------------- SpMM (CSR, wave/row, 8-wide 2-stage reg pipeline) ---------
// MODE 0: prod = acc * aux (aux = x, f32)        -> prodb
// MODE 1: prod = acc * elu(aux) (aux = pre1 f32) -> prodb
// MODE 2: no product
template <int MODE>
__global__ __launch_bounds__(256) void spmm_bf(const int* __restrict__ offs,
                                               const int2* __restrict__ edges,
                                               const short* __restrict__ Xbf,
                                               const float* __restrict__ aux,
                                               short* __restrict__ outb,
                                               short* __restrict__ prodb) {
  int row = blockIdx.x * 4 + (threadIdx.x >> 6);
  int lane = threadIdx.x & 63;
  int h0 = lane * 8;
  float acc[8] = {0.f, 0.f, 0.f, 0.f, 0.f, 0.f, 0.f, 0.f};
  int e0 = offs[row], e1 = offs[row + 1];
  int p = e0;

  int2 ma[8];
  bf16x8 xa[8];
  if (p + 8 <= e1) {
#pragma unroll
    for (int u = 0; u < 8; ++u) ma[u] = edges[p + u];
#pragma unroll
    for (int u = 0; u < 8; ++u)
      xa[u] = *reinterpret_cast<const bf16x8*>(Xbf + (size_t)ma[u].x * HDIM + h0);
    p += 8;
    for (; p + 8 <= e1; p += 8) {
      int2 mb[8];
      bf16x8 xb[8];
#pragma unroll
      for (int u = 0; u < 8; ++u) mb[u] = edges[p + u];
#pragma unroll
      for (int u = 0; u < 8; ++u)
        xb[u] = *reinterpret_cast<const bf16x8*>(Xbf + (size_t)mb[u].x * HDIM + h0);
#pragma unroll
      for (int u = 0; u < 8; ++u) {
        float v = __int_as_float(ma[u].y);
#pragma unroll
        for (int j = 0; j < 8; ++j) acc[j] = fmaf(v, bf2f(xa[u][j]), acc[j]);
      }
#pragma unroll
      for (int u = 0; u < 8; ++u) { ma[u] = mb[u]; xa[u] = xb[u]; }
    }
#pragma unroll
    for (int u = 0; u < 8; ++u) {
      float v = __int_as_float(ma[u].y);
#pragma unroll
      for (int j = 0; j < 8; ++j) acc[j] = fmaf(v, bf2f(xa[u][j]), acc[j]);
    }
  }
  for (; p < e1; ++p) {
    int2 e = edges[p];
    float v = __int_as_float(e.y);
    bf16x8 xr = *reinterpret_cast<const bf16x8*>(Xbf + (size_t)e.x * HDIM + h0);
#pragma unroll
    for (int j = 0; j < 8; ++j) acc[j] = fmaf(v, bf2f(xr[j]), acc[j]);
  }

  bf16x8 o;
#pragma unroll
  for (int j = 0; j < 8; ++j) o[j] = (short)f2bf(acc[j]);
  *reinterpret_cast<bf16x8*>(outb + (size_t)row * 1024 + h0) = o;
  if (MODE != 2) {
    const float4* ap = reinterpret_cast<const float4*>(aux + (size_t)row * HDIM + h0);
    float4 a0 = ap[0], a1 = ap[1];
    float xv[8] = {a0.x, a0.y, a0.z, a0.w, a1.x, a1.y, a1.z, a1.w};
    if (MODE == 1) {
#pragma unroll
      for (int j = 0; j < 8; ++j) xv[j] = xv[j] > 0.f ? xv[j] : expm1f(xv[j]);
    }
    bf16x8 t;
#pragma unroll
    for (int j = 0; j < 8; ++j) t[j] = (short)f2bf(acc[j] * xv[j]);
    *reinterpret_cast<bf16x8*>(prodb + (size_t)row * HDIM + h0) = t;
  }
}

// ---------------- fused prep: x cast + W1/W2 cast + bias ----------------
__device__ inline void cast8(const float* src, short* dst) {
  const float4* p = reinterpret_cast<const float4*>(src);
  float4 a = p[0], b = p[1];
  bf16x8 o;
  o[0] = (short)f2bf(a.x); o[1] = (short)f2bf(a.y);
  o[2] = (short)f2bf(a.z); o[3] = (short)f2bf(a.w);
  o[4] = (short)f2bf(b.x); o[5] = (short)f2bf(b.y);
  o[6] = (short)f2bf(b.z); o[7] = (short)f2bf(b.w);
  *reinterpret_cast<bf16x8*>(dst) = o;
}

__global__ void prep_kernel(const float* __restrict__ x,
                            const float* __restrict__ W1, const float* __restrict__ W2,
                            const float* __restrict__ b1, const float* __restrict__ b2,
                            short* __restrict__ Xbf, short* __restrict__ Bbuf,
                            float* __restrict__ b12) {
  int b = blockIdx.x;
  if (b < 2048) {                 // x: 8192x512 -> Xbf (ld 512)
    int t = b * 256 + threadIdx.x;
    int row = t >> 6, c0 = (t & 63) * 8;
    cast8(x + (size_t)row * 512 + c0, Xbf + (size_t)row * 512 + c0);
  } else if (b < 2176) {          // W1: 512x512 -> Bbuf col 0 (ld 1024)
    int t = (b - 2048) * 256 + threadIdx.x;
    int row = t >> 6, c0 = (t & 63) * 8;
    cast8(W1 + (size_t)row * 512 + c0, Bbuf + (size_t)row * 1024 + c0);
  } else if (b < 2304) {          // W2 -> Bbuf col 512
    int t = (b - 2176) * 256 + threadIdx.x;
    int row = t >> 6, c0 = (t & 63) * 8;
    cast8(W2 + (size_t)row * 512 + c0, Bbuf + (size_t)row * 1024 + 512 + c0);
  } else {                        // bias
    int j = threadIdx.x;
    b12[j] = b1[j] + b2[j];
    b12[j + 256] = b1[j + 256] + b2[j + 256];
  }
}

// ---------------- row L2 normalize + bf16 copy ----------------
__global__ __launch_bounds__(256) void rownorm_kernel(const float* __restrict__ X,
                                                      float* __restrict__ outf,
                                                      short* __restrict__ outb) {
  int row = blockIdx.x * 4 + (threadIdx.x >> 6);
  int lane = threadIdx.x & 63;
  int h0 = lane * 8;
  const float4* p = reinterpret_cast<const float4*>(X + (size_t)row * HDIM + h0);
  float4 a = p[0], b = p[1];
  float s = a.x * a.x + a.y * a.y + a.z * a.z + a.w * a.w +
            b.x * b.x + b.y * b.y + b.z * b.z + b.w * b.w;
#pragma unroll
  for (int off = 1; off < 64; off <<= 1) s += __shfl_xor(s, off, 64);
  float inv = 1.f / fmaxf(sqrtf(s), 1e-12f);
  a.x *= inv; a.y *= inv; a.z *= inv; a.w *= inv;
  b.x *= inv; b.y *= inv; b.z *= inv; b.w *= inv;
  float4* q = reinterpret_cast<float4*>(outf + (size_t)row * HDIM + h0);
  q[0] = a; q[1] = b;
  bf16x8 o;
  o[0] = (short)f2bf(a.x); o[1] = (short)f2bf(a.y);
  o[2] = (short)f2bf(a.z); o[3] = (short)f2bf(a.w);
  o[4] = (short)f2bf(b.x); o[5] = (short)f2bf(b.y);
  o[6] = (short)f2bf(b.z); o[7] = (short)f2bf(b.w);
  *reinterpret_cast<bf16x8*>(outb + (size_t)row * HDIM + h0) = o;
}

// ---------------- LDS-staged bf16 MFMA GEMM (layer GEMMs, 128x128) ----------
// MODE 0: out0 = C + bias (pre, f32, ld N); out1bf = bf16(elu(pre))
// MODE 1: out0 = resid + 0.4*elu(C + bias)
template <int MODE>
__global__ __launch_bounds__(256) void gemm_lds(const short* __restrict__ A,
                                                const short* __restrict__ B,
                                                int N, int K, int nbn,
                                                const float* __restrict__ bias,
                                                const float* __restrict__ resid,
                                                float* __restrict__ out0,
                                                short* __restrict__ out1bf) {
  __shared__ __align__(16) short la[128 * 64];
  __shared__ __align__(16) short lb[128 * 64];

  int q = gridDim.x >> 3;
  int id = (blockIdx.x & 7) * q + (blockIdx.x >> 3);
  int bn = (id % nbn) * 128;
  int bm = (id / nbn) * 128;

  int lane = threadIdx.x & 63;
  int wave = threadIdx.x >> 6;

  int rsub = lane >> 3;
  int csrc = (lane & 7) ^ rsub;
  size_t ldkB = (size_t)K * 2;
  const char* gA0 = (const char*)A + (size_t)(bm + wave * 32 + rsub) * ldkB + csrc * 16;
  const char* gB0 = (const char*)B + (size_t)(bn + wave * 32 + rsub) * ldkB + csrc * 16;
  char* lA0 = (char*)la + wave * 4096;
  char* lB0 = (char*)lb + wave * 4096;

  f32x4 zero = {0.f, 0.f, 0.f, 0.f};
  f32x4 acc[4][4];
#pragma unroll
  for (int m = 0; m < 4; ++m)
#pragma unroll
    for (int n = 0; n < 4; ++n) acc[m][n] = zero;

  int rlo = lane & 15;
  int khi = lane >> 4;
  int wm = wave >> 1, wn = wave & 1;

  for (int k0 = 0; k0 < K; k0 += 64) {
    __syncthreads();
#pragma unroll
    for (int j = 0; j < 4; ++j) {
      gload16(gA0 + (size_t)j * 8 * ldkB + (size_t)k0 * 2, lA0 + j * 1024);
      gload16(gB0 + (size_t)j * 8 * ldkB + (size_t)k0 * 2, lB0 + j * 1024);
    }
    __syncthreads();
#pragma unroll
    for (int kk = 0; kk < 2; ++kk) {
      bf16x8 av[4], bv[4];
#pragma unroll
      for (int m = 0; m < 4; ++m) {
        int ra = wm * 64 + m * 16 + rlo;
        int pc = (kk * 4 + khi) ^ (ra & 7);
        av[m] = *reinterpret_cast<const bf16x8*>((const char*)la + ra * 128 + pc * 16);
      }
#pragma unroll
      for (int n = 0; n < 4; ++n) {
        int rb = wn * 64 + n * 16 + rlo;
        int pc = (kk * 4 + khi) ^ (rb & 7);
        bv[n] = *reinterpret_cast<const bf16x8*>((const char*)lb + rb * 128 + pc * 16);
      }
#pragma unroll
      for (int m = 0; m < 4; ++m)
#pragma unroll
        for (int n = 0; n < 4; ++n)
          acc[m][n] = __builtin_amdgcn_mfma_f32_16x16x32_bf16(av[m], bv[n], acc[m][n], 0, 0, 0);
    }
  }

  int obm = bm + wm * 64;
  int obn = bn + wn * 64;
  int crow = (lane >> 4) * 4;
  int ccol = lane & 15;
#pragma unroll
  for (int n = 0; n < 4; ++n) {
    int c = obn + n * 16 + ccol;
    float bc = bias[c];
#pragma unroll
    for (int m = 0; m < 4; ++m) {
#pragma unroll
      for (int v = 0; v < 4; ++v) {
        int r = obm + m * 16 + crow + v;
        size_t idx = (size_t)r * N + c;
        float val = acc[m][n][v];
        if (MODE == 0) {
          float pvl = val + bc;
          out0[idx] = pvl;
          float e = pvl > 0.f ? pvl : expm1f(pvl);
          out1bf[idx] = (short)f2bf(e);
        } else {
          float pvl = val + bc;
          out0[idx] = resid[idx] + 0.4f * (pvl > 0.f ? pvl : expm1f(pvl));
        }
      }
    }
  }
}

// ---------------- gram: 256x256 tile, 8 waves, K-step 32, 4-deep ring -------
// out = relu(H H^T), H = Hbuf [8192 x 512] bf16. Counted vmcnt (T4), raw
// s_barrier, setprio around MFMA cluster (T5). One barrier per phase.
// Ring slot (32KB): [A 256x32 bf16][B 256x32 bf16]; 4 slots = 128KB LDS.
// Phase s: stage step s+2 -> ring[(s+2)&3] (slot last read 2 barriers ago);
// vmcnt(8)=steps s+1,s+2 outstanding => step s fully resident for ALL threads
// (per-thread FIFO + barrier); then ds_read ring[s&3] + 32 MFMA.
__device__ inline void wait_vmcnt_u(int n) {
  if (n == 8)      asm volatile("s_waitcnt vmcnt(8)" ::: "memory");
  else if (n == 4) asm volatile("s_waitcnt vmcnt(4)" ::: "memory");
  else             asm volatile("s_waitcnt vmcnt(0)" ::: "memory");
}

__global__ __launch_bounds__(512, 2) void gram256(const short* __restrict__ H,
                                                  float* __restrict__ out) {
  __shared__ __align__(16) char lds[4 * 32768];
  const int NK = HDIM / 32;          // 16

  // XCD swizzle (1024 blocks) + 8x8 block supertiles for L2 locality
  int id = (blockIdx.x & 7) * 128 + (blockIdx.x >> 3);
  int sid = id >> 6, wt = id & 63;
  int bm = ((sid >> 2) * 8 + (wt >> 3)) * 256;
  int bn = ((sid & 3) * 8 + (wt & 7)) * 256;

  int tid = threadIdx.x;
  int wid = tid >> 6;
  int lane = tid & 63;
  int wr = wid >> 2;                 // 0..1 (M)
  int wc = wid & 3;                  // 0..3 (N)
  int rlo = lane & 15;
  int khi = lane >> 4;               // 0..3
  int wbase = wid * 1024;

  const char* Ab = (const char*)H + (size_t)bm * 1024;
  const char* Bb = (const char*)H + (size_t)bn * 1024;
  int r4 = tid >> 2, c4 = tid & 3;

  f32x4 zero = {0.f, 0.f, 0.f, 0.f};
  f32x4 acc[8][4];
#pragma unroll
  for (int m = 0; m < 8; ++m)
#pragma unroll
    for (int n = 0; n < 4; ++n) acc[m][n] = zero;

  // stage(s): 4 gload16/thread into ring[s&3]
  auto stage = [&](int s) {
    char* slot = lds + ((s & 3) << 15);
    size_t go = (size_t)s * 64 + c4 * 16;
    gload16(Ab + (size_t)r4 * 1024 + go,          slot + wbase);
    gload16(Ab + (size_t)(r4 + 128) * 1024 + go,  slot + 8192 + wbase);
    gload16(Bb + (size_t)r4 * 1024 + go,          slot + 16384 + wbase);
    gload16(Bb + (size_t)(r4 + 128) * 1024 + go,  slot + 24576 + wbase);
  };

  stage(0);
  stage(1);

  for (int s = 0; s < NK; ++s) {
    if (s + 2 < NK) stage(s + 2);
    int out_cnt = 4 * ((s + 1 < NK) + (s + 2 < NK));
    wait_vmcnt_u(out_cnt);
    __builtin_amdgcn_s_barrier();
    __builtin_amdgcn_sched_barrier(0);

    const char* slot = lds + ((s & 3) << 15);
    bf16x8 av[8], bv[4];
#pragma unroll
    for (int m = 0; m < 8; ++m)
      av[m] = *reinterpret_cast<const bf16x8*>(
          slot + (wr * 128 + m * 16 + rlo) * 64 + khi * 16);
#pragma unroll
    for (int n = 0; n < 4; ++n)
      bv[n] = *reinterpret_cast<const bf16x8*>(
          slot + 16384 + (wc * 64 + n * 16 + rlo) * 64 + khi * 16);

    __builtin_amdgcn_s_setprio(1);
#pragma unroll
    for (int m = 0; m < 8; ++m)
#pragma unroll
      for (int n = 0; n < 4; ++n)
        acc[m][n] = __builtin_amdgcn_mfma_f32_16x16x32_bf16(av[m], bv[n], acc[m][n], 0, 0, 0);
    __builtin_amdgcn_s_setprio(0);
  }

  int obm = bm + wr * 128;
  int obn = bn + wc * 64;
  int crow = khi * 4;
#pragma unroll
  for (int m = 0; m < 8; ++m) {
#pragma unroll
    for (int n = 0; n < 4; ++n) {
      int c = obn + n * 16 + rlo;
#pragma unroll
      for (int v = 0; v < 4; ++v) {
        int r = obm + m * 16 + crow + v;
        float val = acc[m][n][v];
        out[(size_t)r * N_NODES + c] = val > 0.f ? val : 0.f;
      }
    }
  }
}

extern "C" void kernel_launch(void* const* d_in, const int* in_sizes, int n_in,
                              void* d_out, int out_size, void* d_ws, size_t ws_size,
                              hipStream_t stream) {
  const float* x  = (const float*)d_in[0];
  const int* rows = (const int*)d_in[1];
  const int* cols = (const int*)d_in[2];
  const float* vals = (const float*)d_in[3];
  const float* W1 = (const float*)d_in[4];
  const float* b1 = (const float*)d_in[5];
  const float* W2 = (const float*)d_in[6];
  const float* b2 = (const float*)d_in[7];

  float* out_adj = (float*)d_out;
  float* out_hid = out_adj + (size_t)N_NODES * N_NODES;

  char* w = (char*)d_ws;
  size_t off = 0;
  auto alloc = [&](size_t bytes) -> void* {
    void* p = w + off;
    off += (bytes + 255) & ~(size_t)255;
    return p;
  };
  int* counts   = (int*)alloc(8192 * sizeof(int));
  int* offs     = (int*)alloc(8193 * sizeof(int));
  int* cursor   = (int*)alloc(8192 * sizeof(int));
  int2* edges   = (int2*)alloc((size_t)NEDGE * sizeof(int2));
  float* b12    = (float*)alloc(HDIM * sizeof(float));
  short* Xbf    = (short*)alloc((size_t)N_NODES * HDIM * sizeof(short));
  short* Tbf    = (short*)alloc((size_t)N_NODES * HDIM * sizeof(short));
  short* Abuf   = (short*)alloc((size_t)N_NODES * 1024 * sizeof(short));
  short* Bbuf   = (short*)alloc((size_t)512 * 1024 * sizeof(short));
  float* pre1   = (float*)alloc((size_t)N_NODES * HDIM * sizeof(float));
  float* Hf     = (float*)alloc((size_t)N_NODES * HDIM * sizeof(float));
  short* Hbuf   = (short*)alloc((size_t)N_NODES * HDIM * sizeof(short));

  // CSR build (packed (col,val) edge list, row-sorted)
  zero_kernel<<<32, 256, 0, stream>>>(counts);
  hist_kernel<<<NEDGE / 256, 256, 0, stream>>>(rows, counts);
  scan_kernel<<<1, 1024, 0, stream>>>(counts, offs, cursor);
  scatter_kernel<<<NEDGE / 256, 256, 0, stream>>>(rows, cols, vals, cursor, edges);

  // fused prep: x cast, W1/W2 cast, bias
  prep_kernel<<<2305, 256, 0, stream>>>(x, W1, W2, b1, b2, Xbf, Bbuf, b12);

  // ---- layer 1 ----
  spmm_bf<0><<<2048, 256, 0, stream>>>(offs, edges, Xbf, x, Abuf, Tbf);
  spmm_bf<2><<<2048, 256, 0, stream>>>(offs, edges, Tbf, nullptr, Abuf + 512, nullptr);
  // pre1 = [Ax|Axx]@[W1|W2]^T + b12 ; x1_bf = bf16(elu(pre1)) -> Xbf (reuse)
  gemm_lds<0><<<256, 256, 0, stream>>>(Abuf, Bbuf, 512, 1024, 4, b12, nullptr, pre1, Xbf);

  // ---- layer 2 ----
  spmm_bf<1><<<2048, 256, 0, stream>>>(offs, edges, Xbf, pre1, Abuf, Tbf);
  spmm_bf<2><<<2048, 256, 0, stream>>>(offs, edges, Tbf, nullptr, Abuf + 512, nullptr);
  // x2 = pre1 + 0.4*elu([Ax2|Axx2]@[W1|W2]^T + b12) -> Hf
  gemm_lds<1><<<256, 256, 0, stream>>>(Abuf, Bbuf, 512, 1024, 4, b12, pre1, Hf, nullptr);

  // ---- decoder ----
  rownorm_kernel<<<2048, 256, 0, stream>>>(Hf, out_hid, Hbuf);
  gram256<<<1024, 512, 0, stream>>>(Hbuf, out_adj);
}

// Round 7
// 327.287 us; speedup vs baseline: 1.0631x; 1.0631x over previous
//
#include <hip/hip_runtime.h>

#define N_NODES 8192
#define HDIM    512
#define NEDGE   262144

typedef __attribute__((ext_vector_type(8))) short bf16x8;
typedef __attribute__((ext_vector_type(4))) short bf16x4;
typedef __attribute__((ext_vector_type(4))) float f32x4;

__device__ inline unsigned short f2bf(float f) {
  unsigned u = __float_as_uint(f);
  unsigned r = (u + 0x7FFFu + ((u >> 16) & 1u)) >> 16;
  return (unsigned short)r;
}
__device__ inline float bf2f(short s) {
  return __uint_as_float(((unsigned)(unsigned short)s) << 16);
}

__device__ inline void gload16(const void* g, void* l) {
  __builtin_amdgcn_global_load_lds(
      (const __attribute__((address_space(1))) unsigned*)g,
      (__attribute__((address_space(3))) unsigned*)l, 16, 0, 0);
}

// ---------------- CSR build ----------------
__global__ void hist_kernel(const int* __restrict__ rows, int* __restrict__ counts) {
  int e = blockIdx.x * 256 + threadIdx.x;
  atomicAdd(&counts[rows[e]], 1);
}

__global__ __launch_bounds__(1024) void scan_kernel(const int* __restrict__ counts,
                                                    int* __restrict__ offs,
                                                    int* __restrict__ cursor) {
  __shared__ int s[1024];
  int tid = threadIdx.x;
  int local[8];
  int sum = 0;
#pragma unroll
  for (int i = 0; i < 8; ++i) { local[i] = counts[tid * 8 + i]; sum += local[i]; }
  s[tid] = sum;
  __syncthreads();
  for (int d = 1; d < 1024; d <<= 1) {
    int v = (tid >= d) ? s[tid - d] : 0;
    __syncthreads();
    s[tid] += v;
    __syncthreads();
  }
  int base = (tid > 0) ? s[tid - 1] : 0;
#pragma unroll
  for (int i = 0; i < 8; ++i) {
    offs[tid * 8 + i] = base;
    cursor[tid * 8 + i] = base;
    base += local[i];
  }
  if (tid == 1023) offs[8192] = base;
}

__global__ void scatter_kernel(const int* __restrict__ rows, const int* __restrict__ cols,
                               const float* __restrict__ vals, int* cursor,
                               int2* __restrict__ edges) {
  int e = blockIdx.x * 256 + threadIdx.x;
  int slot = atomicAdd(&cursor[rows[e]], 1);
  edges[slot] = make_int2(cols[e], __float_as_int(vals[e]));
}

// ---------------- SpMM (CSR, wave/row, 4-wide 2-stage reg pipeline) ---------
// MODE 0: prod = acc * aux (aux = x, f32)        -> prodb
// MODE 1: prod = acc * elu(aux) (aux = pre1 f32) -> prodb
// MODE 2: no product
template <int MODE>
__global__ __launch_bounds__(256) void spmm_bf(const int* __restrict__ offs,
                                               const int2* __restrict__ edges,
                                               const short* __restrict__ Xbf,
                                               const float* __restrict__ aux,
                                               short* __restrict__ outb,
                                               short* __restrict__ prodb) {
  int row = blockIdx.x * 4 + (threadIdx.x >> 6);
  int lane = threadIdx.x & 63;
  int h0 = lane * 8;
  float acc[8] = {0.f, 0.f, 0.f, 0.f, 0.f, 0.f, 0.f, 0.f};
  int e0 = offs[row], e1 = offs[row + 1];
  int p = e0;

  int2 ma0, ma1, ma2, ma3;
  bf16x8 xa0, xa1, xa2, xa3;

  if (p + 4 <= e1) {
    ma0 = edges[p]; ma1 = edges[p + 1]; ma2 = edges[p + 2]; ma3 = edges[p + 3];
    xa0 = *reinterpret_cast<const bf16x8*>(Xbf + (size_t)ma0.x * HDIM + h0);
    xa1 = *reinterpret_cast<const bf16x8*>(Xbf + (size_t)ma1.x * HDIM + h0);
    xa2 = *reinterpret_cast<const bf16x8*>(Xbf + (size_t)ma2.x * HDIM + h0);
    xa3 = *reinterpret_cast<const bf16x8*>(Xbf + (size_t)ma3.x * HDIM + h0);
    p += 4;
    for (; p + 4 <= e1; p += 4) {
      int2 mb0 = edges[p], mb1 = edges[p + 1], mb2 = edges[p + 2], mb3 = edges[p + 3];
      bf16x8 xb0 = *reinterpret_cast<const bf16x8*>(Xbf + (size_t)mb0.x * HDIM + h0);
      bf16x8 xb1 = *reinterpret_cast<const bf16x8*>(Xbf + (size_t)mb1.x * HDIM + h0);
      bf16x8 xb2 = *reinterpret_cast<const bf16x8*>(Xbf + (size_t)mb2.x * HDIM + h0);
      bf16x8 xb3 = *reinterpret_cast<const bf16x8*>(Xbf + (size_t)mb3.x * HDIM + h0);
      float v0 = __int_as_float(ma0.y), v1 = __int_as_float(ma1.y);
      float v2 = __int_as_float(ma2.y), v3 = __int_as_float(ma3.y);
#pragma unroll
      for (int j = 0; j < 8; ++j) {
        acc[j] = fmaf(v0, bf2f(xa0[j]), acc[j]);
        acc[j] = fmaf(v1, bf2f(xa1[j]), acc[j]);
        acc[j] = fmaf(v2, bf2f(xa2[j]), acc[j]);
        acc[j] = fmaf(v3, bf2f(xa3[j]), acc[j]);
      }
      ma0 = mb0; ma1 = mb1; ma2 = mb2; ma3 = mb3;
      xa0 = xb0; xa1 = xb1; xa2 = xb2; xa3 = xb3;
    }
    {
      float v0 = __int_as_float(ma0.y), v1 = __int_as_float(ma1.y);
      float v2 = __int_as_float(ma2.y), v3 = __int_as_float(ma3.y);
#pragma unroll
      for (int j = 0; j < 8; ++j) {
        acc[j] = fmaf(v0, bf2f(xa0[j]), acc[j]);
        acc[j] = fmaf(v1, bf2f(xa1[j]), acc[j]);
        acc[j] = fmaf(v2, bf2f(xa2[j]), acc[j]);
        acc[j] = fmaf(v3, bf2f(xa3[j]), acc[j]);
      }
    }
  }
  for (; p < e1; ++p) {
    int2 e = edges[p];
    float v = __int_as_float(e.y);
    bf16x8 xr = *reinterpret_cast<const bf16x8*>(Xbf + (size_t)e.x * HDIM + h0);
#pragma unroll
    for (int j = 0; j < 8; ++j) acc[j] = fmaf(v, bf2f(xr[j]), acc[j]);
  }

  bf16x8 o;
#pragma unroll
  for (int j = 0; j < 8; ++j) o[j] = (short)f2bf(acc[j]);
  *reinterpret_cast<bf16x8*>(outb + (size_t)row * 1024 + h0) = o;
  if (MODE != 2) {
    const float4* ap = reinterpret_cast<const float4*>(aux + (size_t)row * HDIM + h0);
    float4 a0 = ap[0], a1 = ap[1];
    float xv[8] = {a0.x, a0.y, a0.z, a0.w, a1.x, a1.y, a1.z, a1.w};
    if (MODE == 1) {
#pragma unroll
      for (int j = 0; j < 8; ++j) xv[j] = xv[j] > 0.f ? xv[j] : expm1f(xv[j]);
    }
    bf16x8 t;
#pragma unroll
    for (int j = 0; j < 8; ++j) t[j] = (short)f2bf(acc[j] * xv[j]);
    *reinterpret_cast<bf16x8*>(prodb + (size_t)row * HDIM + h0) = t;
  }
}

// ---------------- fused prep: x cast + W1/W2 cast + bias ----------------
__device__ inline void cast8(const float* src, short* dst) {
  const float4* p = reinterpret_cast<const float4*>(src);
  float4 a = p[0], b = p[1];
  bf16x8 o;
  o[0] = (short)f2bf(a.x); o[1] = (short)f2bf(a.y);
  o[2] = (short)f2bf(a.z); o[3] = (short)f2bf(a.w);
  o[4] = (short)f2bf(b.x); o[5] = (short)f2bf(b.y);
  o[6] = (short)f2bf(b.z); o[7] = (short)f2bf(b.w);
  *reinterpret_cast<bf16x8*>(dst) = o;
}

__global__ void prep_kernel(const float* __restrict__ x,
                            const float* __restrict__ W1, const float* __restrict__ W2,
                            const float* __restrict__ b1, const float* __restrict__ b2,
                            short* __restrict__ Xbf, short* __restrict__ Bbuf,
                            float* __restrict__ b12) {
  int b = blockIdx.x;
  if (b < 2048) {                 // x: 8192x512 -> Xbf (ld 512)
    int t = b * 256 + threadIdx.x;
    int row = t >> 6, c0 = (t & 63) * 8;
    cast8(x + (size_t)row * 512 + c0, Xbf + (size_t)row * 512 + c0);
  } else if (b < 2176) {          // W1: 512x512 -> Bbuf col 0 (ld 1024)
    int t = (b - 2048) * 256 + threadIdx.x;
    int row = t >> 6, c0 = (t & 63) * 8;
    cast8(W1 + (size_t)row * 512 + c0, Bbuf + (size_t)row * 1024 + c0);
  } else if (b < 2304) {          // W2 -> Bbuf col 512
    int t = (b - 2176) * 256 + threadIdx.x;
    int row = t >> 6, c0 = (t & 63) * 8;
    cast8(W2 + (size_t)row * 512 + c0, Bbuf + (size_t)row * 1024 + 512 + c0);
  } else {                        // bias
    int j = threadIdx.x;
    b12[j] = b1[j] + b2[j];
    b12[j + 256] = b1[j + 256] + b2[j + 256];
  }
}

// ---------------- row L2 normalize + bf16 copy ----------------
__global__ __launch_bounds__(256) void rownorm_kernel(const float* __restrict__ X,
                                                      float* __restrict__ outf,
                                                      short* __restrict__ outb) {
  int row = blockIdx.x * 4 + (threadIdx.x >> 6);
  int lane = threadIdx.x & 63;
  int h0 = lane * 8;
  const float4* p = reinterpret_cast<const float4*>(X + (size_t)row * HDIM + h0);
  float4 a = p[0], b = p[1];
  float s = a.x * a.x + a.y * a.y + a.z * a.z + a.w * a.w +
            b.x * b.x + b.y * b.y + b.z * b.z + b.w * b.w;
#pragma unroll
  for (int off = 1; off < 64; off <<= 1) s += __shfl_xor(s, off, 64);
  float inv = 1.f / fmaxf(sqrtf(s), 1e-12f);
  a.x *= inv; a.y *= inv; a.z *= inv; a.w *= inv;
  b.x *= inv; b.y *= inv; b.z *= inv; b.w *= inv;
  float4* q = reinterpret_cast<float4*>(outf + (size_t)row * HDIM + h0);
  q[0] = a; q[1] = b;
  bf16x8 o;
  o[0] = (short)f2bf(a.x); o[1] = (short)f2bf(a.y);
  o[2] = (short)f2bf(a.z); o[3] = (short)f2bf(a.w);
  o[4] = (short)f2bf(b.x); o[5] = (short)f2bf(b.y);
  o[6] = (short)f2bf(b.z); o[7] = (short)f2bf(b.w);
  *reinterpret_cast<bf16x8*>(outb + (size_t)row * HDIM + h0) = o;
}

// ---------------- LDS-staged bf16 MFMA GEMM (layer GEMMs, 128x128) ----------
// MODE 0: out0 = C + bias (pre, f32, ld N); out1bf = bf16(elu(pre))
// MODE 1: out0 = resid + 0.4*elu(C + bias)
template <int MODE>
__global__ __launch_bounds__(256) void gemm_lds(const short* __restrict__ A,
                                                const short* __restrict__ B,
                                                int N, int K, int nbn,
                                                const float* __restrict__ bias,
                                                const float* __restrict__ resid,
                                                float* __restrict__ out0,
                                                short* __restrict__ out1bf) {
  __shared__ __align__(16) short la[128 * 64];
  __shared__ __align__(16) short lb[128 * 64];

  int q = gridDim.x >> 3;
  int id = (blockIdx.x & 7) * q + (blockIdx.x >> 3);
  int bn = (id % nbn) * 128;
  int bm = (id / nbn) * 128;

  int lane = threadIdx.x & 63;
  int wave = threadIdx.x >> 6;

  int rsub = lane >> 3;
  int csrc = (lane & 7) ^ rsub;
  size_t ldkB = (size_t)K * 2;
  const char* gA0 = (const char*)A + (size_t)(bm + wave * 32 + rsub) * ldkB + csrc * 16;
  const char* gB0 = (const char*)B + (size_t)(bn + wave * 32 + rsub) * ldkB + csrc * 16;
  char* lA0 = (char*)la + wave * 4096;
  char* lB0 = (char*)lb + wave * 4096;

  f32x4 zero = {0.f, 0.f, 0.f, 0.f};
  f32x4 acc[4][4];
#pragma unroll
  for (int m = 0; m < 4; ++m)
#pragma unroll
    for (int n = 0; n < 4; ++n) acc[m][n] = zero;

  int rlo = lane & 15;
  int khi = lane >> 4;
  int wm = wave >> 1, wn = wave & 1;

  for (int k0 = 0; k0 < K; k0 += 64) {
    __syncthreads();
#pragma unroll
    for (int j = 0; j < 4; ++j) {
      gload16(gA0 + (size_t)j * 8 * ldkB + (size_t)k0 * 2, lA0 + j * 1024);
      gload16(gB0 + (size_t)j * 8 * ldkB + (size_t)k0 * 2, lB0 + j * 1024);
    }
    __syncthreads();
#pragma unroll
    for (int kk = 0; kk < 2; ++kk) {
      bf16x8 av[4], bv[4];
#pragma unroll
      for (int m = 0; m < 4; ++m) {
        int ra = wm * 64 + m * 16 + rlo;
        int pc = (kk * 4 + khi) ^ (ra & 7);
        av[m] = *reinterpret_cast<const bf16x8*>((const char*)la + ra * 128 + pc * 16);
      }
#pragma unroll
      for (int n = 0; n < 4; ++n) {
        int rb = wn * 64 + n * 16 + rlo;
        int pc = (kk * 4 + khi) ^ (rb & 7);
        bv[n] = *reinterpret_cast<const bf16x8*>((const char*)lb + rb * 128 + pc * 16);
      }
#pragma unroll
      for (int m = 0; m < 4; ++m)
#pragma unroll
        for (int n = 0; n < 4; ++n)
          acc[m][n] = __builtin_amdgcn_mfma_f32_16x16x32_bf16(av[m], bv[n], acc[m][n], 0, 0, 0);
    }
  }

  int obm = bm + wm * 64;
  int obn = bn + wn * 64;
  int crow = (lane >> 4) * 4;
  int ccol = lane & 15;
#pragma unroll
  for (int n = 0; n < 4; ++n) {
    int c = obn + n * 16 + ccol;
    float bc = bias[c];
#pragma unroll
    for (int m = 0; m < 4; ++m) {
#pragma unroll
      for (int v = 0; v < 4; ++v) {
        int r = obm + m * 16 + crow + v;
        size_t idx = (size_t)r * N + c;
        float val = acc[m][n][v];
        if (MODE == 0) {
          float pvl = val + bc;
          out0[idx] = pvl;
          float e = pvl > 0.f ? pvl : expm1f(pvl);
          out1bf[idx] = (short)f2bf(e);
        } else {
          float pvl = val + bc;
          out0[idx] = resid[idx] + 0.4f * (pvl > 0.f ? pvl : expm1f(pvl));
        }
      }
    }
  }
}

// ---------------- gram v2: 128x256 tile, 8 waves (2x4), 64x64/wave ----------
// out = relu(H H^T). 3-slot 24KB ring (72KB/block, 2 blocks/CU), depth-1
// prefetch, counted vmcnt(3) (T4), setprio around MFMA (T5), 1 barrier/phase.
// WAR-safe: stage(s+1) writes slot (s+1)%3, last read at phase s-2, sealed by
// barrier(s-1) which every thread passes before any thread issues stage(s+1).
// LDS rows 64B stride; wave fragment reads cover a dense 1KB -> conflict-free.
__global__ __launch_bounds__(512, 4) void gram256(const short* __restrict__ H,
                                                  float* __restrict__ out) {
  __shared__ __align__(16) char lds[3 * 24576];
  const int NK = HDIM / 32;          // 16

  // XCD swizzle (2048 blocks, 256/XCD) + 4x4 block supertiles (128 total)
  int id = (blockIdx.x & 7) * 256 + (blockIdx.x >> 3);
  int st = id >> 4, wt = id & 15;    // st 0..127, wt 0..15
  int bm = ((st >> 3) * 4 + (wt >> 2)) * 128;   // bmI 0..63
  int bn = ((st & 7) * 4 + (wt & 3)) * 256;     // bnI 0..31

  int tid = threadIdx.x;
  int wid = tid >> 6;
  int lane = tid & 63;
  int wr = wid >> 2;                 // 0..1 (M)
  int wc = wid & 3;                  // 0..3 (N)
  int rlo = lane & 15;
  int khi = lane >> 4;               // 0..3
  int wbase = wid * 1024;

  const char* Ab = (const char*)H + (size_t)bm * 1024;
  const char* Bb = (const char*)H + (size_t)bn * 1024;
  int r4 = tid >> 2, c4 = tid & 3;   // r4 0..127, c4 0..3

  f32x4 zero = {0.f, 0.f, 0.f, 0.f};
  f32x4 acc[4][4];
#pragma unroll
  for (int m = 0; m < 4; ++m)
#pragma unroll
    for (int n = 0; n < 4; ++n) acc[m][n] = zero;

  // slot layout: [A 128x32 bf16 (8KB)][B0 128x32 (8KB)][B1 128x32 (8KB)]
  auto stage = [&](int s) {
    char* slot = lds + (s % 3) * 24576;
    size_t go = (size_t)s * 64 + c4 * 16;
    gload16(Ab + (size_t)r4 * 1024 + go,         slot + wbase);
    gload16(Bb + (size_t)r4 * 1024 + go,         slot + 8192 + wbase);
    gload16(Bb + (size_t)(r4 + 128) * 1024 + go, slot + 16384 + wbase);
  };

  stage(0);

  for (int s = 0; s < NK; ++s) {
    if (s + 1 < NK) {
      stage(s + 1);
      asm volatile("s_waitcnt vmcnt(3)" ::: "memory");   // retire stage(s)
    } else {
      asm volatile("s_waitcnt vmcnt(0)" ::: "memory");
    }
    __builtin_amdgcn_s_barrier();
    __builtin_amdgcn_sched_barrier(0);

    const char* slot = lds + (s % 3) * 24576;
    bf16x8 av[4], bv[4];
#pragma unroll
    for (int m = 0; m < 4; ++m)
      av[m] = *reinterpret_cast<const bf16x8*>(
          slot + (wr * 64 + m * 16 + rlo) * 64 + khi * 16);
#pragma unroll
    for (int n = 0; n < 4; ++n)
      bv[n] = *reinterpret_cast<const bf16x8*>(
          slot + 8192 + (wc * 64 + n * 16 + rlo) * 64 + khi * 16);

    __builtin_amdgcn_s_setprio(1);
#pragma unroll
    for (int m = 0; m < 4; ++m)
#pragma unroll
      for (int n = 0; n < 4; ++n)
        acc[m][n] = __builtin_amdgcn_mfma_f32_16x16x32_bf16(av[m], bv[n], acc[m][n], 0, 0, 0);
    __builtin_amdgcn_s_setprio(0);
  }

  int obm = bm + wr * 64;
  int obn = bn + wc * 64;
  int crow = khi * 4;
#pragma unroll
  for (int m = 0; m < 4; ++m) {
#pragma unroll
    for (int n = 0; n < 4; ++n) {
      int c = obn + n * 16 + rlo;
#pragma unroll
      for (int v = 0; v < 4; ++v) {
        int r = obm + m * 16 + crow + v;
        float val = acc[m][n][v];
        out[(size_t)r * N_NODES + c] = val > 0.f ? val : 0.f;
      }
    }
  }
}

extern "C" void kernel_launch(void* const* d_in, const int* in_sizes, int n_in,
                              void* d_out, int out_size, void* d_ws, size_t ws_size,
                              hipStream_t stream) {
  const float* x  = (const float*)d_in[0];
  const int* rows = (const int*)d_in[1];
  const int* cols = (const int*)d_in[2];
  const float* vals = (const float*)d_in[3];
  const float* W1 = (const float*)d_in[4];
  const float* b1 = (const float*)d_in[5];
  const float* W2 = (const float*)d_in[6];
  const float* b2 = (const float*)d_in[7];

  float* out_adj = (float*)d_out;
  float* out_hid = out_adj + (size_t)N_NODES * N_NODES;

  char* w = (char*)d_ws;
  size_t off = 0;
  auto alloc = [&](size_t bytes) -> void* {
    void* p = w + off;
    off += (bytes + 255) & ~(size_t)255;
    return p;
  };
  int* counts   = (int*)alloc(8192 * sizeof(int));
  int* offs     = (int*)alloc(8193 * sizeof(int));
  int* cursor   = (int*)alloc(8192 * sizeof(int));
  int2* edges   = (int2*)alloc((size_t)NEDGE * sizeof(int2));
  float* b12    = (float*)alloc(HDIM * sizeof(float));
  short* Xbf    = (short*)alloc((size_t)N_NODES * HDIM * sizeof(short));
  short* Tbf    = (short*)alloc((size_t)N_NODES * HDIM * sizeof(short));
  short* Abuf   = (short*)alloc((size_t)N_NODES * 1024 * sizeof(short));
  short* Bbuf   = (short*)alloc((size_t)512 * 1024 * sizeof(short));
  float* pre1   = (float*)alloc((size_t)N_NODES * HDIM * sizeof(float));
  float* Hf     = (float*)alloc((size_t)N_NODES * HDIM * sizeof(float));
  short* Hbuf   = (short*)alloc((size_t)N_NODES * HDIM * sizeof(short));

  // CSR build (packed (col,val) edge list, row-sorted)
  hipMemsetAsync(counts, 0, 8192 * sizeof(int), stream);
  hist_kernel<<<NEDGE / 256, 256, 0, stream>>>(rows, counts);
  scan_kernel<<<1, 1024, 0, stream>>>(counts, offs, cursor);
  scatter_kernel<<<NEDGE / 256, 256, 0, stream>>>(rows, cols, vals, cursor, edges);

  // fused prep: x cast, W1/W2 cast, bias
  prep_kernel<<<2305, 256, 0, stream>>>(x, W1, W2, b1, b2, Xbf, Bbuf, b12);

  // ---- layer 1 ----
  spmm_bf<0><<<2048, 256, 0, stream>>>(offs, edges, Xbf, x, Abuf, Tbf);
  spmm_bf<2><<<2048, 256, 0, stream>>>(offs, edges, Tbf, nullptr, Abuf + 512, nullptr);
  // pre1 = [Ax|Axx]@[W1|W2]^T + b12 ; x1_bf = bf16(elu(pre1)) -> Xbf (reuse)
  gemm_lds<0><<<256, 256, 0, stream>>>(Abuf, Bbuf, 512, 1024, 4, b12, nullptr, pre1, Xbf);

  // ---- layer 2 ----
  spmm_bf<1><<<2048, 256, 0, stream>>>(offs, edges, Xbf, pre1, Abuf, Tbf);
  spmm_bf<2><<<2048, 256, 0, stream>>>(offs, edges, Tbf, nullptr, Abuf + 512, nullptr);
  // x2 = pre1 + 0.4*elu([Ax2|Axx2]@[W1|W2]^T + b12) -> Hf
  gemm_lds<1><<<256, 256, 0, stream>>>(Abuf, Bbuf, 512, 1024, 4, b12, pre1, Hf, nullptr);

  // ---- decoder ----
  rownorm_kernel<<<2048, 256, 0, stream>>>(Hf, out_hid, Hbuf);
  gram256<<<2048, 512, 0, stream>>>(Hbuf, out_adj);
}

// Round 8
// 315.721 us; speedup vs baseline: 1.1020x; 1.0366x over previous
//
#include <hip/hip_runtime.h>

#define N_NODES 8192
#define HDIM    512
#define NEDGE   262144

typedef __attribute__((ext_vector_type(8))) short bf16x8;
typedef __attribute__((ext_vector_type(4))) float f32x4;

__device__ inline unsigned short f2bf(float f) {
  unsigned u = __float_as_uint(f);
  unsigned r = (u + 0x7FFFu + ((u >> 16) & 1u)) >> 16;
  return (unsigned short)r;
}
__device__ inline float bf2f(short s) {
  return __uint_as_float(((unsigned)(unsigned short)s) << 16);
}

__device__ inline void gload16(const void* g, void* l) {
  __builtin_amdgcn_global_load_lds(
      (const __attribute__((address_space(1))) unsigned*)g,
      (__attribute__((address_space(3))) unsigned*)l, 16, 0, 0);
}

__device__ inline void wait_vmcnt_c(int n) {
  if (n == 8)      asm volatile("s_waitcnt vmcnt(8)" ::: "memory");
  else if (n == 4) asm volatile("s_waitcnt vmcnt(4)" ::: "memory");
  else if (n == 3) asm volatile("s_waitcnt vmcnt(3)" ::: "memory");
  else             asm volatile("s_waitcnt vmcnt(0)" ::: "memory");
}

// ---------------- CSR build ----------------
__global__ __launch_bounds__(1024) void scan_kernel(const int* __restrict__ counts,
                                                    int* __restrict__ offs,
                                                    int* __restrict__ cursor) {
  __shared__ int s[1024];
  int tid = threadIdx.x;
  int local[8];
  int sum = 0;
#pragma unroll
  for (int i = 0; i < 8; ++i) { local[i] = counts[tid * 8 + i]; sum += local[i]; }
  s[tid] = sum;
  __syncthreads();
  for (int d = 1; d < 1024; d <<= 1) {
    int v = (tid >= d) ? s[tid - d] : 0;
    __syncthreads();
    s[tid] += v;
    __syncthreads();
  }
  int base = (tid > 0) ? s[tid - 1] : 0;
#pragma unroll
  for (int i = 0; i < 8; ++i) {
    offs[tid * 8 + i] = base;
    cursor[tid * 8 + i] = base;
    base += local[i];
  }
  if (tid == 1023) offs[8192] = base;
}

__global__ void scatter_kernel(const int* __restrict__ rows, const int* __restrict__ cols,
                               const float* __restrict__ vals, int* cursor,
                               int2* __restrict__ edges) {
  int e = blockIdx.x * 256 + threadIdx.x;
  int slot = atomicAdd(&cursor[rows[e]], 1);
  edges[slot] = make_int2(cols[e], __float_as_int(vals[e]));
}

// ---------------- SpMM (CSR, wave/row, 4-wide 2-stage reg pipeline) ---------
// MODE 0: prod = acc * aux (aux = x, f32)        -> prodb
// MODE 1: prod = acc * elu(aux) (aux = pre1 f32) -> prodb
// MODE 2: no product
template <int MODE>
__global__ __launch_bounds__(256) void spmm_bf(const int* __restrict__ offs,
                                               const int2* __restrict__ edges,
                                               const short* __restrict__ Xbf,
                                               const float* __restrict__ aux,
                                               short* __restrict__ outb,
                                               short* __restrict__ prodb) {
  int row = blockIdx.x * 4 + (threadIdx.x >> 6);
  int lane = threadIdx.x & 63;
  int h0 = lane * 8;
  float acc[8] = {0.f, 0.f, 0.f, 0.f, 0.f, 0.f, 0.f, 0.f};
  int e0 = offs[row], e1 = offs[row + 1];
  int p = e0;

  int2 ma0, ma1, ma2, ma3;
  bf16x8 xa0, xa1, xa2, xa3;

  if (p + 4 <= e1) {
    ma0 = edges[p]; ma1 = edges[p + 1]; ma2 = edges[p + 2]; ma3 = edges[p + 3];
    xa0 = *reinterpret_cast<const bf16x8*>(Xbf + (size_t)ma0.x * HDIM + h0);
    xa1 = *reinterpret_cast<const bf16x8*>(Xbf + (size_t)ma1.x * HDIM + h0);
    xa2 = *reinterpret_cast<const bf16x8*>(Xbf + (size_t)ma2.x * HDIM + h0);
    xa3 = *reinterpret_cast<const bf16x8*>(Xbf + (size_t)ma3.x * HDIM + h0);
    p += 4;
    for (; p + 4 <= e1; p += 4) {
      int2 mb0 = edges[p], mb1 = edges[p + 1], mb2 = edges[p + 2], mb3 = edges[p + 3];
      bf16x8 xb0 = *reinterpret_cast<const bf16x8*>(Xbf + (size_t)mb0.x * HDIM + h0);
      bf16x8 xb1 = *reinterpret_cast<const bf16x8*>(Xbf + (size_t)mb1.x * HDIM + h0);
      bf16x8 xb2 = *reinterpret_cast<const bf16x8*>(Xbf + (size_t)mb2.x * HDIM + h0);
      bf16x8 xb3 = *reinterpret_cast<const bf16x8*>(Xbf + (size_t)mb3.x * HDIM + h0);
      float v0 = __int_as_float(ma0.y), v1 = __int_as_float(ma1.y);
      float v2 = __int_as_float(ma2.y), v3 = __int_as_float(ma3.y);
#pragma unroll
      for (int j = 0; j < 8; ++j) {
        acc[j] = fmaf(v0, bf2f(xa0[j]), acc[j]);
        acc[j] = fmaf(v1, bf2f(xa1[j]), acc[j]);
        acc[j] = fmaf(v2, bf2f(xa2[j]), acc[j]);
        acc[j] = fmaf(v3, bf2f(xa3[j]), acc[j]);
      }
      ma0 = mb0; ma1 = mb1; ma2 = mb2; ma3 = mb3;
      xa0 = xb0; xa1 = xb1; xa2 = xb2; xa3 = xb3;
    }
    {
      float v0 = __int_as_float(ma0.y), v1 = __int_as_float(ma1.y);
      float v2 = __int_as_float(ma2.y), v3 = __int_as_float(ma3.y);
#pragma unroll
      for (int j = 0; j < 8; ++j) {
        acc[j] = fmaf(v0, bf2f(xa0[j]), acc[j]);
        acc[j] = fmaf(v1, bf2f(xa1[j]), acc[j]);
        acc[j] = fmaf(v2, bf2f(xa2[j]), acc[j]);
        acc[j] = fmaf(v3, bf2f(xa3[j]), acc[j]);
      }
    }
  }
  for (; p < e1; ++p) {
    int2 e = edges[p];
    float v = __int_as_float(e.y);
    bf16x8 xr = *reinterpret_cast<const bf16x8*>(Xbf + (size_t)e.x * HDIM + h0);
#pragma unroll
    for (int j = 0; j < 8; ++j) acc[j] = fmaf(v, bf2f(xr[j]), acc[j]);
  }

  bf16x8 o;
#pragma unroll
  for (int j = 0; j < 8; ++j) o[j] = (short)f2bf(acc[j]);
  *reinterpret_cast<bf16x8*>(outb + (size_t)row * 1024 + h0) = o;
  if (MODE != 2) {
    const float4* ap = reinterpret_cast<const float4*>(aux + (size_t)row * HDIM + h0);
    float4 a0 = ap[0], a1 = ap[1];
    float xv[8] = {a0.x, a0.y, a0.z, a0.w, a1.x, a1.y, a1.z, a1.w};
    if (MODE == 1) {
#pragma unroll
      for (int j = 0; j < 8; ++j) xv[j] = xv[j] > 0.f ? xv[j] : expm1f(xv[j]);
    }
    bf16x8 t;
#pragma unroll
    for (int j = 0; j < 8; ++j) t[j] = (short)f2bf(acc[j] * xv[j]);
    *reinterpret_cast<bf16x8*>(prodb + (size_t)row * HDIM + h0) = t;
  }
}

// ---------------- fused prep: hist + x cast + W1/W2 cast + bias -------------
__device__ inline void cast8(const float* src, short* dst) {
  const float4* p = reinterpret_cast<const float4*>(src);
  float4 a = p[0], b = p[1];
  bf16x8 o;
  o[0] = (short)f2bf(a.x); o[1] = (short)f2bf(a.y);
  o[2] = (short)f2bf(a.z); o[3] = (short)f2bf(a.w);
  o[4] = (short)f2bf(b.x); o[5] = (short)f2bf(b.y);
  o[6] = (short)f2bf(b.z); o[7] = (short)f2bf(b.w);
  *reinterpret_cast<bf16x8*>(dst) = o;
}

__global__ void prep_kernel(const int* __restrict__ rows, int* __restrict__ counts,
                            const float* __restrict__ x,
                            const float* __restrict__ W1, const float* __restrict__ W2,
                            const float* __restrict__ b1, const float* __restrict__ b2,
                            short* __restrict__ Xbf, short* __restrict__ Bbuf,
                            float* __restrict__ b12) {
  int b = blockIdx.x;
  if (b < 1024) {                 // hist
    int e = b * 256 + threadIdx.x;
    atomicAdd(&counts[rows[e]], 1);
  } else if (b < 3072) {          // x: 8192x512 -> Xbf (ld 512)
    int t = (b - 1024) * 256 + threadIdx.x;
    int row = t >> 6, c0 = (t & 63) * 8;
    cast8(x + (size_t)row * 512 + c0, Xbf + (size_t)row * 512 + c0);
  } else if (b < 3200) {          // W1: 512x512 -> Bbuf col 0 (ld 1024)
    int t = (b - 3072) * 256 + threadIdx.x;
    int row = t >> 6, c0 = (t & 63) * 8;
    cast8(W1 + (size_t)row * 512 + c0, Bbuf + (size_t)row * 1024 + c0);
  } else if (b < 3328) {          // W2 -> Bbuf col 512
    int t = (b - 3200) * 256 + threadIdx.x;
    int row = t >> 6, c0 = (t & 63) * 8;
    cast8(W2 + (size_t)row * 512 + c0, Bbuf + (size_t)row * 1024 + 512 + c0);
  } else {                        // bias
    int j = threadIdx.x;
    b12[j] = b1[j] + b2[j];
    b12[j + 256] = b1[j + 256] + b2[j + 256];
  }
}

// ---------------- row L2 normalize + bf16 copy ----------------
__global__ __launch_bounds__(256) void rownorm_kernel(const float* __restrict__ X,
                                                      float* __restrict__ outf,
                                                      short* __restrict__ outb) {
  int row = blockIdx.x * 4 + (threadIdx.x >> 6);
  int lane = threadIdx.x & 63;
  int h0 = lane * 8;
  const float4* p = reinterpret_cast<const float4*>(X + (size_t)row * HDIM + h0);
  float4 a = p[0], b = p[1];
  float s = a.x * a.x + a.y * a.y + a.z * a.z + a.w * a.w +
            b.x * b.x + b.y * b.y + b.z * b.z + b.w * b.w;
#pragma unroll
  for (int off = 1; off < 64; off <<= 1) s += __shfl_xor(s, off, 64);
  float inv = 1.f / fmaxf(sqrtf(s), 1e-12f);
  a.x *= inv; a.y *= inv; a.z *= inv; a.w *= inv;
  b.x *= inv; b.y *= inv; b.z *= inv; b.w *= inv;
  float4* q = reinterpret_cast<float4*>(outf + (size_t)row * HDIM + h0);
  q[0] = a; q[1] = b;
  bf16x8 o;
  o[0] = (short)f2bf(a.x); o[1] = (short)f2bf(a.y);
  o[2] = (short)f2bf(a.z); o[3] = (short)f2bf(a.w);
  o[4] = (short)f2bf(b.x); o[5] = (short)f2bf(b.y);
  o[6] = (short)f2bf(b.z); o[7] = (short)f2bf(b.w);
  *reinterpret_cast<bf16x8*>(outb + (size_t)row * HDIM + h0) = o;
}

// ---------------- layer GEMM: 128x128 tile, 4 waves, K-phase 32, ring -------
// C[M,N] = A[M,K]*B[N,K]^T. 3-slot ring (slot = A 128x32 + B 128x32 = 16KB),
// stage-after-barrier depth-2, counted vmcnt(4) (never 0 mid-loop).
// MODE 0: out0 = C + bias (f32, ld N); out1bf = bf16(elu(out0))
// MODE 1: out0 = resid + 0.4*elu(C + bias)
template <int MODE>
__global__ __launch_bounds__(256) void gemm_ring(const short* __restrict__ A,
                                                 const short* __restrict__ B,
                                                 int N, int K, int nbn,
                                                 const float* __restrict__ bias,
                                                 const float* __restrict__ resid,
                                                 float* __restrict__ out0,
                                                 short* __restrict__ out1bf) {
  __shared__ __align__(16) char lds[3 * 16384];
  int NK = K >> 5;

  int q = gridDim.x >> 3;
  int id = (blockIdx.x & 7) * q + (blockIdx.x >> 3);
  int bn = (id % nbn) * 128;
  int bm = (id / nbn) * 128;

  int tid = threadIdx.x;
  int wid = tid >> 6;
  int lane = tid & 63;
  int wm = wid >> 1, wn = wid & 1;
  int rlo = lane & 15;
  int khi = lane >> 4;
  int wbase = wid * 1024;          // wave-uniform LDS base for gload16

  size_t ldkB = (size_t)K * 2;
  const char* Ab = (const char*)A + (size_t)bm * ldkB;
  const char* Bb = (const char*)B + (size_t)bn * ldkB;
  int r4 = tid >> 2, c4 = tid & 3;  // r4 0..63, c4 0..3

  f32x4 zero = {0.f, 0.f, 0.f, 0.f};
  f32x4 acc[4][4];
#pragma unroll
  for (int m = 0; m < 4; ++m)
#pragma unroll
    for (int n = 0; n < 4; ++n) acc[m][n] = zero;

  // slot: [A rows 0..127 x 64B][B rows 0..127 x 64B]
  auto stage = [&](int s) {
    char* slot = lds + (s % 3) * 16384;
    size_t go = (size_t)s * 64 + c4 * 16;
    gload16(Ab + (size_t)r4 * ldkB + go,         slot + wbase);
    gload16(Ab + (size_t)(r4 + 64) * ldkB + go,  slot + 4096 + wbase);
    gload16(Bb + (size_t)r4 * ldkB + go,         slot + 8192 + wbase);
    gload16(Bb + (size_t)(r4 + 64) * ldkB + go,  slot + 12288 + wbase);
  };

  stage(0);
  stage(1);

  for (int s = 0; s < NK; ++s) {
    wait_vmcnt_c((s + 1 < NK) ? 4 : 0);   // retire stage(s); stage(s+1) stays in flight
    __builtin_amdgcn_s_barrier();
    __builtin_amdgcn_sched_barrier(0);
    if (s + 2 < NK) stage(s + 2);         // safe: barrier sealed phase s-1 reads

    const char* slot = lds + (s % 3) * 16384;
    bf16x8 av[4], bv[4];
#pragma unroll
    for (int m = 0; m < 4; ++m)
      av[m] = *reinterpret_cast<const bf16x8*>(
          slot + (wm * 64 + m * 16 + rlo) * 64 + khi * 16);
#pragma unroll
    for (int n = 0; n < 4; ++n)
      bv[n] = *reinterpret_cast<const bf16x8*>(
          slot + 8192 + (wn * 64 + n * 16 + rlo) * 64 + khi * 16);

    __builtin_amdgcn_s_setprio(1);
#pragma unroll
    for (int m = 0; m < 4; ++m)
#pragma unroll
      for (int n = 0; n < 4; ++n)
        acc[m][n] = __builtin_amdgcn_mfma_f32_16x16x32_bf16(av[m], bv[n], acc[m][n], 0, 0, 0);
    __builtin_amdgcn_s_setprio(0);
  }

  int obm = bm + wm * 64;
  int obn = bn + wn * 64;
  int crow = khi * 4;
#pragma unroll
  for (int n = 0; n < 4; ++n) {
    int c = obn + n * 16 + rlo;
    float bc = bias[c];
#pragma unroll
    for (int m = 0; m < 4; ++m) {
#pragma unroll
      for (int v = 0; v < 4; ++v) {
        int r = obm + m * 16 + crow + v;
        size_t idx = (size_t)r * N + c;
        float val = acc[m][n][v];
        if (MODE == 0) {
          float pvl = val + bc;
          out0[idx] = pvl;
          float e = pvl > 0.f ? pvl : expm1f(pvl);
          out1bf[idx] = (short)f2bf(e);
        } else {
          float pvl = val + bc;
          out0[idx] = resid[idx] + 0.4f * (pvl > 0.f ? pvl : expm1f(pvl));
        }
      }
    }
  }
}

// ---------------- gram: 128x256 tile, 8 waves (2x4), 64x64/wave, ring -------
// out = relu(H H^T). 3-slot 24KB ring, stage-after-barrier depth-2,
// counted vmcnt(3), setprio around MFMA, 1 barrier/phase.
__global__ __launch_bounds__(512, 4) void gram256(const short* __restrict__ H,
                                                  float* __restrict__ out) {
  __shared__ __align__(16) char lds[3 * 24576];
  const int NK = HDIM / 32;          // 16

  // XCD swizzle (2048 blocks, 256/XCD) + 4x4 block supertiles (128 total)
  int id = (blockIdx.x & 7) * 256 + (blockIdx.x >> 3);
  int st = id >> 4, wt = id & 15;
  int bm = ((st >> 3) * 4 + (wt >> 2)) * 128;
  int bn = ((st & 7) * 4 + (wt & 3)) * 256;

  int tid = threadIdx.x;
  int wid = tid >> 6;
  int lane = tid & 63;
  int wr = wid >> 2;                 // 0..1 (M)
  int wc = wid & 3;                  // 0..3 (N)
  int rlo = lane & 15;
  int khi = lane >> 4;
  int wbase = wid * 1024;

  const char* Ab = (const char*)H + (size_t)bm * 1024;
  const char* Bb = (const char*)H + (size_t)bn * 1024;
  int r4 = tid >> 2, c4 = tid & 3;   // r4 0..127

  f32x4 zero = {0.f, 0.f, 0.f, 0.f};
  f32x4 acc[4][4];
#pragma unroll
  for (int m = 0; m < 4; ++m)
#pragma unroll
    for (int n = 0; n < 4; ++n) acc[m][n] = zero;

  // slot layout: [A 128x32 (8KB)][B0 128x32 (8KB)][B1 128x32 (8KB)]
  auto stage = [&](int s) {
    char* slot = lds + (s % 3) * 24576;
    size_t go = (size_t)s * 64 + c4 * 16;
    gload16(Ab + (size_t)r4 * 1024 + go,         slot + wbase);
    gload16(Bb + (size_t)r4 * 1024 + go,         slot + 8192 + wbase);
    gload16(Bb + (size_t)(r4 + 128) * 1024 + go, slot + 16384 + wbase);
  };

  stage(0);
  stage(1);

  for (int s = 0; s < NK; ++s) {
    wait_vmcnt_c((s + 1 < NK) ? 3 : 0);
    __builtin_amdgcn_s_barrier();
    __builtin_amdgcn_sched_barrier(0);
    if (s + 2 < NK) stage(s + 2);

    const char* slot = lds + (s % 3) * 24576;
    bf16x8 av[4], bv[4];
#pragma unroll
    for (int m = 0; m < 4; ++m)
      av[m] = *reinterpret_cast<const bf16x8*>(
          slot + (wr * 64 + m * 16 + rlo) * 64 + khi * 16);
#pragma unroll
    for (int n = 0; n < 4; ++n)
      bv[n] = *reinterpret_cast<const bf16x8*>(
          slot + 8192 + (wc * 64 + n * 16 + rlo) * 64 + khi * 16);

    __builtin_amdgcn_s_setprio(1);
#pragma unroll
    for (int m = 0; m < 4; ++m)
#pragma unroll
      for (int n = 0; n < 4; ++n)
        acc[m][n] = __builtin_amdgcn_mfma_f32_16x16x32_bf16(av[m], bv[n], acc[m][n], 0, 0, 0);
    __builtin_amdgcn_s_setprio(0);
  }

  int obm = bm + wr * 64;
  int obn = bn + wc * 64;
  int crow = khi * 4;
#pragma unroll
  for (int m = 0; m < 4; ++m) {
#pragma unroll
    for (int n = 0; n < 4; ++n) {
      int c = obn + n * 16 + rlo;
#pragma unroll
      for (int v = 0; v < 4; ++v) {
        int r = obm + m * 16 + crow + v;
        float val = acc[m][n][v];
        out[(size_t)r * N_NODES + c] = val > 0.f ? val : 0.f;
      }
    }
  }
}

extern "C" void kernel_launch(void* const* d_in, const int* in_sizes, int n_in,
                              void* d_out, int out_size, void* d_ws, size_t ws_size,
                              hipStream_t stream) {
  const float* x  = (const float*)d_in[0];
  const int* rows = (const int*)d_in[1];
  const int* cols = (const int*)d_in[2];
  const float* vals = (const float*)d_in[3];
  const float* W1 = (const float*)d_in[4];
  const float* b1 = (const float*)d_in[5];
  const float* W2 = (const float*)d_in[6];
  const float* b2 = (const float*)d_in[7];

  float* out_adj = (float*)d_out;
  float* out_hid = out_adj + (size_t)N_NODES * N_NODES;

  char* w = (char*)d_ws;
  size_t off = 0;
  auto alloc = [&](size_t bytes) -> void* {
    void* p = w + off;
    off += (bytes + 255) & ~(size_t)255;
    return p;
  };
  int* counts   = (int*)alloc(8192 * sizeof(int));
  int* offs     = (int*)alloc(8193 * sizeof(int));
  int* cursor   = (int*)alloc(8192 * sizeof(int));
  int2* edges   = (int2*)alloc((size_t)NEDGE * sizeof(int2));
  float* b12    = (float*)alloc(HDIM * sizeof(float));
  short* Xbf    = (short*)alloc((size_t)N_NODES * HDIM * sizeof(short));
  short* Tbf    = (short*)alloc((size_t)N_NODES * HDIM * sizeof(short));
  short* Abuf   = (short*)alloc((size_t)N_NODES * 1024 * sizeof(short));
  short* Bbuf   = (short*)alloc((size_t)512 * 1024 * sizeof(short));
  float* pre1   = (float*)alloc((size_t)N_NODES * HDIM * sizeof(float));
  float* Hf     = (float*)alloc((size_t)N_NODES * HDIM * sizeof(float));
  short* Hbuf   = (short*)alloc((size_t)N_NODES * HDIM * sizeof(short));

  // CSR build + prep (hist fused into prep)
  hipMemsetAsync(counts, 0, 8192 * sizeof(int), stream);
  prep_kernel<<<3329, 256, 0, stream>>>(rows, counts, x, W1, W2, b1, b2, Xbf, Bbuf, b12);
  scan_kernel<<<1, 1024, 0, stream>>>(counts, offs, cursor);
  scatter_kernel<<<NEDGE / 256, 256, 0, stream>>>(rows, cols, vals, cursor, edges);

  // ---- layer 1 ----
  spmm_bf<0><<<2048, 256, 0, stream>>>(offs, edges, Xbf, x, Abuf, Tbf);
  spmm_bf<2><<<2048, 256, 0, stream>>>(offs, edges, Tbf, nullptr, Abuf + 512, nullptr);
  // pre1 = [Ax|Axx]@[W1|W2]^T + b12 ; x1_bf = bf16(elu(pre1)) -> Xbf (reuse)
  gemm_ring<0><<<256, 256, 0, stream>>>(Abuf, Bbuf, 512, 1024, 4, b12, nullptr, pre1, Xbf);

  // ---- layer 2 ----
  spmm_bf<1><<<2048, 256, 0, stream>>>(offs, edges, Xbf, pre1, Abuf, Tbf);
  spmm_bf<2><<<2048, 256, 0, stream>>>(offs, edges, Tbf, nullptr, Abuf + 512, nullptr);
  // x2 = pre1 + 0.4*elu([Ax2|Axx2]@[W1|W2]^T + b12) -> Hf
  gemm_ring<1><<<256, 256, 0, stream>>>(Abuf, Bbuf, 512, 1024, 4, b12, pre1, Hf, nullptr);

  // ---- decoder ----
  rownorm_kernel<<<2048, 256, 0, stream>>>(Hf, out_hid, Hbuf);
  gram256<<<2048, 512, 0, stream>>>(Hbuf, out_adj);
}